// Round 10
// baseline (207.712 us; speedup 1.0000x reference)
//
#include <hip/hip_runtime.h>
#include <hip/hip_fp16.h>

// ---------------- types ----------------
typedef __attribute__((ext_vector_type(8))) short short8;
typedef __attribute__((ext_vector_type(4))) float f32x4;

#define GLOBAL_AS __attribute__((address_space(1)))
#define LDS_AS __attribute__((address_space(3)))

static __device__ __forceinline__ void gload16(const void* g, void* l) {
    __builtin_amdgcn_global_load_lds((const GLOBAL_AS void*)g, (LDS_AS void*)l, 16, 0, 0);
}

#define SBAR() __builtin_amdgcn_s_barrier()
#define WAITVM(N) asm volatile("s_waitcnt vmcnt(" #N ")" ::: "memory")

// float -> bf16 RNE via bit trick
static __device__ __forceinline__ unsigned short f2bf(float f) {
    union { float f; unsigned u; } v; v.f = f;
    unsigned r = v.u + 0x7FFFu + ((v.u >> 16) & 1u);
    return (unsigned short)(r >> 16);
}

// ---------------- kernel 1: fused prep (unchanged from round 8) ----------------
__global__ __launch_bounds__(256) void prep_kernel(
    const int* __restrict__ packed,      // [4096][2048] one byte value per int
    const float* __restrict__ scales,    // [4096]
    const void* __restrict__ vals,       // [nnz] dtype auto-detected
    const int* __restrict__ idxs,        // [nnz]
    const int* __restrict__ ptr,         // [4097]
    uint4* __restrict__ Wb4,             // [4096][512] uint4 = 8 bf16
    const float* __restrict__ x,
    unsigned short* __restrict__ xb)
{
    if (blockIdx.x >= 4096) {
        const int n8 = (4096 * 4096) / 8;
        const int stride = 2048 * 256;
        for (int j = (blockIdx.x - 4096) * 256 + threadIdx.x; j < n8; j += stride) {
            const float4 a = ((const float4*)x)[2 * (size_t)j];
            const float4 b = ((const float4*)x)[2 * (size_t)j + 1];
            short8 o;
            o[0] = (short)f2bf(a.x); o[1] = (short)f2bf(a.y);
            o[2] = (short)f2bf(a.z); o[3] = (short)f2bf(a.w);
            o[4] = (short)f2bf(b.x); o[5] = (short)f2bf(b.y);
            o[6] = (short)f2bf(b.z); o[7] = (short)f2bf(b.w);
            *(short8*)(xb + 8 * (size_t)j) = o;
        }
        return;
    }
    __shared__ float sp[4096];
    __shared__ int sc[3];
    const int row = blockIdx.x;
    float4* sp4 = (float4*)sp;
    const float4 z4 = make_float4(0.f, 0.f, 0.f, 0.f);
    for (int i = threadIdx.x; i < 1024; i += 256) sp4[i] = z4;
    {
        const int wvp = threadIdx.x >> 6, ln = threadIdx.x & 63;
        if (wvp < 3) {
            int c = 0;
            for (int i = ln; i < 192; i += 64) {
                float a;
                if (wvp == 0) a = fabsf(((const float*)vals)[i]);
                else if (wvp == 1) a = fabsf(__half2float(((const __half*)vals)[i]));
                else { union { unsigned u; float fv; } cc;
                       cc.u = ((unsigned)((const unsigned short*)vals)[i]) << 16;
                       a = fabsf(cc.fv); }
                c += (a >= 1e-5f && a <= 0.5f) ? 1 : 0;
            }
            for (int o = 32; o; o >>= 1) c += __shfl_down(c, o);
            if (ln == 0) sc[wvp] = c;
        }
    }
    __syncthreads();
    const int kind = (sc[0] >= sc[1] && sc[0] >= sc[2]) ? 0 : (sc[1] >= sc[2] ? 1 : 2);
    const int s = ptr[row], e = ptr[row + 1];
    if (kind == 0) {
        const float* vf = (const float*)vals;
        for (int i = s + threadIdx.x; i < e; i += 256) atomicAdd(&sp[idxs[i]], vf[i]);
    } else if (kind == 1) {
        const __half* vh = (const __half*)vals;
        for (int i = s + threadIdx.x; i < e; i += 256) atomicAdd(&sp[idxs[i]], __half2float(vh[i]));
    } else {
        const unsigned short* vb = (const unsigned short*)vals;
        for (int i = s + threadIdx.x; i < e; i += 256) {
            union { unsigned u; float fv; } c; c.u = ((unsigned)vb[i]) << 16;
            atomicAdd(&sp[idxs[i]], c.fv);
        }
    }
    __syncthreads();
    const float sc_ = scales[row];
    const int4* prow4 = (const int4*)(packed + (size_t)row * 2048);
    uint4* wrow4 = Wb4 + (size_t)row * 512;
    for (int j = threadIdx.x; j < 512; j += 256) {
        const int4 p = prow4[j];
        const float* spc = sp + 8 * j;
        uint4 o;
        o.x = (unsigned)f2bf((float)((p.x & 0xF) - 8) * sc_ + spc[0]) |
              ((unsigned)f2bf((float)(((p.x >> 4) & 0xF) - 8) * sc_ + spc[1]) << 16);
        o.y = (unsigned)f2bf((float)((p.y & 0xF) - 8) * sc_ + spc[2]) |
              ((unsigned)f2bf((float)(((p.y >> 4) & 0xF) - 8) * sc_ + spc[3]) << 16);
        o.z = (unsigned)f2bf((float)((p.z & 0xF) - 8) * sc_ + spc[4]) |
              ((unsigned)f2bf((float)(((p.z >> 4) & 0xF) - 8) * sc_ + spc[5]) << 16);
        o.w = (unsigned)f2bf((float)((p.w & 0xF) - 8) * sc_ + spc[6]) |
              ((unsigned)f2bf((float)(((p.w >> 4) & 0xF) - 8) * sc_ + spc[7]) << 16);
        wrow4[j] = o;
    }
}

// ---------------- kernel 2: 256x256 GEMM, A in LDS (4 slots), B direct-to-reg ----------------
// C[M,N]=A[M,K]*B[N,K]^T, 16x16x32 bf16, 8 waves (2Mx4N), wave 128x64, BK=64.
// Round-10: LDS-BW reduction. Per K-tile LDS traffic was 256KB (>= MFMA floor);
// B has only 2x intra-block reuse (wr pair loads identical addresses -> L2 hit)
// so B fragments now load global->VGPR directly (the dwordx4 IS the fragment:
// row n*16+(lane&15), k-seg (lane>>4)*8). LDS now A-only: 160KB/K-tile.
// Pipeline (free-running, r8 style): per tile issue [B(t+1)x8 regs, A(t+2)x4
// gload_lds]; ONE gate WAITVM(4) at tile top (FIFO: leaves exactly A(t+1);
// drains A(t),B(t)). Compiler's dataflow vmcnt backstops B-reg uses; the gate
// backstops LDS reads (untrackable by compiler). bpA/bpB ping-pong via 2x
// unrolled loop (static indexing only). A staging/swizzle identical to r8
// (measured 0 bank conflicts). 4 A-slots = 128KB.
__global__ __launch_bounds__(512, 2) void gemm_bt_kernel(
    const unsigned short* __restrict__ A,   // bf16 bits, M x K
    const unsigned short* __restrict__ B,   // bf16 bits, N x K
    float* __restrict__ C)                  // fp32, M x N
{
    constexpr int K = 4096;
    constexpr int N = 4096;
    constexpr int NT = K / 64;   // 64 K-tiles
    __shared__ __attribute__((aligned(128))) char smem[131072]; // 4 A-slots x 32KB

    const int tid = threadIdx.x;
    const int lane = tid & 63;
    const int wv = tid >> 6;              // 0..7
    const int bid = (blockIdx.x & 7) * 32 + (blockIdx.x >> 3);  // bijective XCD swizzle
    const int bm = bid >> 4;              // 16 M-tiles
    const int bn = bid & 15;              // 16 N-tiles

    // ---- A staging: one gload16 round (512 thr x 16B = 8KB) = 64 rows x 128B ----
    const int grow = tid >> 3;                          // 0..63 row within round
    const int sg = (tid & 7) ^ (grow & 7);              // pre-swizzled 16B segment
    const unsigned short* ag = A + (size_t)(bm * 256 + grow) * K + sg * 8;

#define STA2a(KT, SLOT)                                                                \
    { gload16(ag + (size_t)(0 * 64) * K + (KT), smem + (SLOT) * 32768 + 0 * 8192 + wv * 1024); \
      gload16(ag + (size_t)(1 * 64) * K + (KT), smem + (SLOT) * 32768 + 1 * 8192 + wv * 1024); }
#define STA2b(KT, SLOT)                                                                \
    { gload16(ag + (size_t)(2 * 64) * K + (KT), smem + (SLOT) * 32768 + 2 * 8192 + wv * 1024); \
      gload16(ag + (size_t)(3 * 64) * K + (KT), smem + (SLOT) * 32768 + 3 * 8192 + wv * 1024); }

    // ---- fragment read geometry ----
    const int wr = wv >> 2, wc = wv & 3;                // 2x4 wave grid
    const int rowa = wr * 128 + (lane & 15);            // + mh*64 + m*16
    const int khw = lane >> 4;                          // 0..3
    const int rx = lane & 7;

#define LDA4(DST, MH, KK, SLOT)                                                        \
    {                                                                                  \
        _Pragma("unroll") for (int m = 0; m < 4; ++m) {                                \
            const int row_ = rowa + (MH) * 64 + m * 16;                                \
            DST[m] = *(const short8*)(smem + (SLOT) * 32768 + row_ * 128 +             \
                                      (((((KK) << 2) + khw) ^ rx) << 4));              \
        }                                                                              \
    }

    // ---- B direct loads: lane's fragment slice, per (n, kk) ----
    const unsigned short* bgr = B + (size_t)(bn * 256 + wc * 64 + (lane & 15)) * K + khw * 8;
#define LDB1(ARR, I, NN, KKX, KT)                                                      \
    ARR[I] = *(const short8*)(bgr + (size_t)(NN) * 16 * K + (KT) + (KKX) * 32);

#define MFMA16(AF, BP, KO, MH)                                                         \
    {                                                                                  \
        __builtin_amdgcn_s_setprio(1);                                                 \
        _Pragma("unroll") for (int m = 0; m < 4; ++m)                                  \
            _Pragma("unroll") for (int n = 0; n < 4; ++n)                              \
                acc[(MH) * 4 + m][n] = __builtin_amdgcn_mfma_f32_16x16x32_bf16(        \
                    AF[m], BP[(KO) + n], acc[(MH) * 4 + m][n], 0, 0, 0);               \
        __builtin_amdgcn_s_setprio(0);                                                 \
    }

    f32x4 acc[8][4];
#pragma unroll
    for (int m = 0; m < 8; ++m)
#pragma unroll
        for (int n = 0; n < 4; ++n) acc[m][n] = (f32x4)0.0f;

    short8 bpA[8], bpB[8];

    // ---- prologue: B(0) regs (8), then A(0)@s0, A(1)@s1 (8 gloads) ----
    LDB1(bpA, 0, 0, 0, 0); LDB1(bpA, 1, 1, 0, 0);
    LDB1(bpA, 2, 2, 0, 0); LDB1(bpA, 3, 3, 0, 0);
    LDB1(bpA, 4, 0, 1, 0); LDB1(bpA, 5, 1, 1, 0);
    LDB1(bpA, 6, 2, 1, 0); LDB1(bpA, 7, 3, 1, 0);
    STA2a(0, 0); STA2b(0, 0);
    STA2a(64, 1); STA2b(64, 1);

    // TILE(T): consume A-slot T&3 and BPC; issue B(t+1)->BPN, A(t+2)->slot
#define TILE(T, BPC, BPN)                                                              \
    {                                                                                  \
        const int sC = (T) & 3, sN2 = ((T) + 2) & 3;                                   \
        const int ktn = ((T) + 1) * 64, ktn2 = ((T) + 2) * 64;                         \
        const bool h1 = (T) + 1 < NT, h2 = (T) + 2 < NT;                               \
        if (h1) { WAITVM(4); } else { WAITVM(0); }                                     \
        SBAR();                                                                        \
        __builtin_amdgcn_sched_barrier(0);                                             \
        short8 af0[4], af1[4];                                                         \
        LDA4(af0, 0, 0, sC);                                                           \
        if (h1) { LDB1(BPN, 0, 0, 0, ktn); LDB1(BPN, 1, 1, 0, ktn);                    \
                  LDB1(BPN, 2, 2, 0, ktn); LDB1(BPN, 3, 3, 0, ktn); }                  \
        MFMA16(af0, BPC, 0, 0);                                                        \
        LDA4(af1, 1, 0, sC);                                                           \
        if (h1) { LDB1(BPN, 4, 0, 1, ktn); LDB1(BPN, 5, 1, 1, ktn);                    \
                  LDB1(BPN, 6, 2, 1, ktn); LDB1(BPN, 7, 3, 1, ktn); }                  \
        MFMA16(af1, BPC, 0, 1);                                                        \
        LDA4(af0, 0, 1, sC);                                                           \
        if (h2) { STA2a(ktn2, sN2); }                                                  \
        MFMA16(af0, BPC, 4, 0);                                                        \
        LDA4(af1, 1, 1, sC);                                                           \
        if (h2) { STA2b(ktn2, sN2); }                                                  \
        MFMA16(af1, BPC, 4, 1);                                                        \
    }

    for (int tt = 0; tt < NT; tt += 2) {
        TILE(tt, bpA, bpB);
        TILE(tt + 1, bpB, bpA);
    }

    // ---- epilogue: C/D layout col=lane&15, row=(lane>>4)*4+reg ----
    const int crow0 = bm * 256 + wr * 128 + (lane >> 4) * 4;
    const int ccol0 = bn * 256 + wc * 64 + (lane & 15);
#pragma unroll
    for (int m = 0; m < 8; ++m)
#pragma unroll
        for (int n = 0; n < 4; ++n)
#pragma unroll
            for (int r = 0; r < 4; ++r)
                C[(size_t)(crow0 + m * 16 + r) * N + ccol0 + n * 16] = acc[m][n][r];
}

// ---------------- launch ----------------
extern "C" void kernel_launch(void* const* d_in, const int* in_sizes, int n_in,
                              void* d_out, int out_size, void* d_ws, size_t ws_size,
                              hipStream_t stream) {
    const float* x        = (const float*)d_in[0];
    const int* packed     = (const int*)d_in[1];
    const float* scales   = (const float*)d_in[2];
    const void* vals      = (const void*)d_in[3];
    const int* idxs       = (const int*)d_in[4];
    const int* ptr        = (const int*)d_in[5];
    float* out            = (float*)d_out;

    unsigned short* Wb = (unsigned short*)d_ws;            // 4096*4096 bf16 = 32 MB
    unsigned short* Xb = Wb + (size_t)4096 * 4096;         // next 32 MB

    prep_kernel<<<6144, 256, 0, stream>>>(packed, scales, vals, idxs, ptr,
                                          (uint4*)Wb, x, Xb);
    gemm_bt_kernel<<<256, 512, 0, stream>>>(Xb, Wb, out);
}

// Round 11
// 99.676 us; speedup vs baseline: 2.0839x; 2.0839x over previous
//
#include <hip/hip_runtime.h>
#include <hip/hip_fp16.h>

// ---------------- types ----------------
typedef __attribute__((ext_vector_type(4))) int i32x4;

#define GLOBAL_AS __attribute__((address_space(1)))
#define LDS_AS __attribute__((address_space(3)))

static __device__ __forceinline__ void gload16(const void* g, void* l) {
    __builtin_amdgcn_global_load_lds((const GLOBAL_AS void*)g, (LDS_AS void*)l, 16, 0, 0);
}

#define SBAR() __builtin_amdgcn_s_barrier()
#define WAITVM(N) asm volatile("s_waitcnt vmcnt(" #N ")" ::: "memory")

static __device__ __forceinline__ int q8(float v, float inv) {
    int q = (int)rintf(v * inv);
    q = q > 127 ? 127 : q;
    q = q < -127 ? -127 : q;
    return q & 255;
}

// ---------------- kernel 1: fused prep -> int8 operands ----------------
// blocks [0,4096): W row -> i8 (int4 dequant + CSR outliers, per-row absmax scale)
// blocks [4096,8192): X row -> i8 (per-token-row absmax scale)
__global__ __launch_bounds__(256) void prep_kernel(
    const int* __restrict__ packed,      // [4096][2048]
    const float* __restrict__ scales,    // [4096]
    const void* __restrict__ vals,       // [nnz] dtype auto-detected (round-1 finding)
    const int* __restrict__ idxs,        // [nnz]
    const int* __restrict__ ptr,         // [4097]
    int* __restrict__ Wq,                // [4096][1024] ints (4096 i8/row)
    const float* __restrict__ x,
    int* __restrict__ Xq,                // [4096][1024] ints
    float* __restrict__ sw,              // [4096] W row scales
    float* __restrict__ sx)              // [4096] X row scales
{
    const int tid = threadIdx.x;
    __shared__ float smax[4];
    if (blockIdx.x >= 4096) {
        // ---- X row quantize ----
        const int row = blockIdx.x - 4096;
        const float4* xp4 = (const float4*)(x + (size_t)row * 4096);
        float4 v0 = xp4[tid], v1 = xp4[tid + 256], v2 = xp4[tid + 512], v3 = xp4[tid + 768];
        float am = fabsf(v0.x);
        am = fmaxf(am, fabsf(v0.y)); am = fmaxf(am, fabsf(v0.z)); am = fmaxf(am, fabsf(v0.w));
        am = fmaxf(am, fabsf(v1.x)); am = fmaxf(am, fabsf(v1.y)); am = fmaxf(am, fabsf(v1.z)); am = fmaxf(am, fabsf(v1.w));
        am = fmaxf(am, fabsf(v2.x)); am = fmaxf(am, fabsf(v2.y)); am = fmaxf(am, fabsf(v2.z)); am = fmaxf(am, fabsf(v2.w));
        am = fmaxf(am, fabsf(v3.x)); am = fmaxf(am, fabsf(v3.y)); am = fmaxf(am, fabsf(v3.z)); am = fmaxf(am, fabsf(v3.w));
        for (int o = 32; o; o >>= 1) am = fmaxf(am, __shfl_xor(am, o));
        if ((tid & 63) == 0) smax[tid >> 6] = am;
        __syncthreads();
        am = fmaxf(fmaxf(smax[0], smax[1]), fmaxf(smax[2], smax[3]));
        const float sc_ = am > 1e-30f ? am / 127.0f : 0.0f;
        const float inv = am > 1e-30f ? 127.0f / am : 0.0f;
        if (tid == 0) sx[row] = sc_;
        int* orow = Wq ? (Xq + (size_t)row * 1024) : nullptr;  // keep simple; Wq non-null
        orow = Xq + (size_t)row * 1024;
        orow[tid]       = q8(v0.x,inv) | (q8(v0.y,inv)<<8) | (q8(v0.z,inv)<<16) | (q8(v0.w,inv)<<24);
        orow[tid + 256] = q8(v1.x,inv) | (q8(v1.y,inv)<<8) | (q8(v1.z,inv)<<16) | (q8(v1.w,inv)<<24);
        orow[tid + 512] = q8(v2.x,inv) | (q8(v2.y,inv)<<8) | (q8(v2.z,inv)<<16) | (q8(v2.w,inv)<<24);
        orow[tid + 768] = q8(v3.x,inv) | (q8(v3.y,inv)<<8) | (q8(v3.z,inv)<<16) | (q8(v3.w,inv)<<24);
        return;
    }
    // ---- W row dequant + outliers -> i8 ----
    __shared__ float sp[4096];
    __shared__ int sdet[3];
    const int row = blockIdx.x;
    float4* sp4 = (float4*)sp;
    const float4 z4 = make_float4(0.f, 0.f, 0.f, 0.f);
    for (int i = tid; i < 1024; i += 256) sp4[i] = z4;
    {   // parallel dtype detect (wave w scores interpretation w)
        const int wvp = tid >> 6, ln = tid & 63;
        if (wvp < 3) {
            int c = 0;
            for (int i = ln; i < 192; i += 64) {
                float a;
                if (wvp == 0) a = fabsf(((const float*)vals)[i]);
                else if (wvp == 1) a = fabsf(__half2float(((const __half*)vals)[i]));
                else { union { unsigned u; float fv; } cc;
                       cc.u = ((unsigned)((const unsigned short*)vals)[i]) << 16;
                       a = fabsf(cc.fv); }
                c += (a >= 1e-5f && a <= 0.5f) ? 1 : 0;
            }
            for (int o = 32; o; o >>= 1) c += __shfl_down(c, o);
            if (ln == 0) sdet[wvp] = c;
        }
    }
    __syncthreads();
    const int kind = (sdet[0] >= sdet[1] && sdet[0] >= sdet[2]) ? 0 : (sdet[1] >= sdet[2] ? 1 : 2);
    const int s = ptr[row], e = ptr[row + 1];
    if (kind == 0) {
        const float* vf = (const float*)vals;
        for (int i = s + tid; i < e; i += 256) atomicAdd(&sp[idxs[i]], vf[i]);
    } else if (kind == 1) {
        const __half* vh = (const __half*)vals;
        for (int i = s + tid; i < e; i += 256) atomicAdd(&sp[idxs[i]], __half2float(vh[i]));
    } else {
        const unsigned short* vb = (const unsigned short*)vals;
        for (int i = s + tid; i < e; i += 256) {
            union { unsigned u; float fv; } c; c.u = ((unsigned)vb[i]) << 16;
            atomicAdd(&sp[idxs[i]], c.fv);
        }
    }
    __syncthreads();
    // pass2: full weight into sp, track absmax
    const float scr = scales[row];
    const int* prow = packed + (size_t)row * 2048;
    float am = 0.0f;
    for (int j = tid; j < 2048; j += 256) {
        const int p = prow[j];
        const float lo = (float)((p & 0xF) - 8) * scr + sp[2 * j];
        const float hi = (float)(((p >> 4) & 0xF) - 8) * scr + sp[2 * j + 1];
        sp[2 * j] = lo; sp[2 * j + 1] = hi;
        am = fmaxf(am, fmaxf(fabsf(lo), fabsf(hi)));
    }
    for (int o = 32; o; o >>= 1) am = fmaxf(am, __shfl_xor(am, o));
    if ((tid & 63) == 0) smax[tid >> 6] = am;
    __syncthreads();
    am = fmaxf(fmaxf(smax[0], smax[1]), fmaxf(smax[2], smax[3]));
    const float sc2 = am > 1e-30f ? am / 127.0f : 0.0f;
    const float inv2 = am > 1e-30f ? 127.0f / am : 0.0f;
    if (tid == 0) sw[row] = sc2;
    int* wrow = Wq + (size_t)row * 1024;
    for (int j = tid; j < 1024; j += 256) {
        const float* c4 = sp + 4 * j;
        wrow[j] = q8(c4[0],inv2) | (q8(c4[1],inv2)<<8) | (q8(c4[2],inv2)<<16) | (q8(c4[3],inv2)<<24);
    }
}

// ---------------- kernel 2: 256x256 GEMM, i8 MFMA, r8 structure verbatim ----------------
// C[M,N] = sx[m]*sw[n]*(Xq[M,K] . Wq[N,K]^T), mfma_i32_16x16x64_i8, 8 waves
// (2Mx4N), wave 128x64, BK=128 i8 (=128B LDS rows -> swizzle/slots identical to
// r8's measured-0-conflict geometry). 5x32KB circular slots, free-running, one
// WAITVM(4)+SBAR per K-tile (r8 ledger: queue at top = B(t)x4,A(t+1)x4).
__global__ __launch_bounds__(512, 2) void gemm_bt_kernel(
    const signed char* __restrict__ A,   // i8, M x 4096
    const signed char* __restrict__ B,   // i8, N x 4096
    const float* __restrict__ sx,        // [M]
    const float* __restrict__ sw,        // [N]
    float* __restrict__ C)               // fp32, M x N
{
    constexpr int KB = 4096;             // K bytes per row
    constexpr int N = 4096;
    constexpr int NT = 32;               // 4096 / 128
    __shared__ __attribute__((aligned(128))) char smem[163840]; // 5 x 32KB slots

    const int tid = threadIdx.x;
    const int lane = tid & 63;
    const int wv = tid >> 6;
    const int bid = (blockIdx.x & 7) * 32 + (blockIdx.x >> 3);  // bijective XCD swizzle
    const int bm = bid >> 4;
    const int bn = bid & 15;

    // ---- staging: one gload16 round (512x16B = 8KB) = 64 rows x 128B ----
    const int grow = tid >> 3;
    const int sg = (tid & 7) ^ (grow & 7);              // pre-swizzled 16B segment
    const signed char* ag = A + (size_t)(bm * 256 + grow) * KB + sg * 16;
    const signed char* bg = B + (size_t)(bn * 256 + grow) * KB + sg * 16;

#define STA(R, KTB, SLOT)                                                              \
    gload16(ag + (size_t)((R) * 64) * KB + (KTB),                                      \
            smem + (SLOT) * 32768 + (R) * 8192 + wv * 1024);
#define STB(R, KTB, SLOT)                                                              \
    gload16(bg + (size_t)((R) * 64) * KB + (KTB),                                      \
            smem + (SLOT) * 32768 + (R) * 8192 + wv * 1024);

    // ---- fragment read geometry (16x16x64 i8: lane&15=row, lane>>4=16B k-seg) ----
    const int wr = wv >> 2, wc = wv & 3;
    const int rowa = wr * 128 + (lane & 15);
    const int rowb = wc * 64 + (lane & 15);
    const int khw = lane >> 4;
    const int rx = lane & 7;

#define LDA4(DST, MH, KK, SLOT)                                                        \
    {                                                                                  \
        _Pragma("unroll") for (int m = 0; m < 4; ++m) {                                \
            const int row_ = rowa + (MH) * 64 + m * 16;                                \
            DST[m] = *(const i32x4*)(smem + (SLOT) * 32768 + row_ * 128 +              \
                                     (((((KK) << 2) + khw) ^ rx) << 4));               \
        }                                                                              \
    }
#define LDB4(DST, KK, SLOT)                                                            \
    {                                                                                  \
        _Pragma("unroll") for (int n = 0; n < 4; ++n) {                                \
            const int row_ = rowb + n * 16;                                            \
            DST[n] = *(const i32x4*)(smem + (SLOT) * 32768 + row_ * 128 +              \
                                     (((((KK) << 2) + khw) ^ rx) << 4));               \
        }                                                                              \
    }
#define MFMA16(AF, BF, MH)                                                             \
    {                                                                                  \
        __builtin_amdgcn_s_setprio(1);                                                 \
        _Pragma("unroll") for (int m = 0; m < 4; ++m)                                  \
            _Pragma("unroll") for (int n = 0; n < 4; ++n)                              \
                acc[(MH) * 4 + m][n] = __builtin_amdgcn_mfma_i32_16x16x64_i8(          \
                    AF[m], BF[n], acc[(MH) * 4 + m][n], 0, 0, 0);                      \
        __builtin_amdgcn_s_setprio(0);                                                 \
    }

    i32x4 acc[8][4];
#pragma unroll
    for (int m = 0; m < 8; ++m)
#pragma unroll
        for (int n = 0; n < 4; ++n) acc[m][n] = (i32x4)0;

    // ---- prologue: A(0)@s0, B(0)@s1, A(1)@s2 ----
#pragma unroll
    for (int r = 0; r < 4; ++r) STA(r, 0, 0);
#pragma unroll
    for (int r = 0; r < 4; ++r) STB(r, 0, 1);
#pragma unroll
    for (int r = 0; r < 4; ++r) STA(r, 128, 2);

    int sA = 0, sB = 1, sB1 = 3, sA2 = 4;
    for (int t = 0; t < NT; ++t) {
        const int ktn = (t + 1) * 128;
        const int ktn2 = (t + 2) * 128;
        const bool s1 = (t + 1 < NT), s2 = (t + 2 < NT);
        if (s1) { WAITVM(4); } else { WAITVM(0); }
        SBAR();
        __builtin_amdgcn_sched_barrier(0);

        i32x4 af0[4], af1[4], bf0[4], bf1[4];
        LDA4(af0, 0, 0, sA); LDB4(bf0, 0, sB);
        if (s1) { STB(0, ktn, sB1); STB(1, ktn, sB1); }
        MFMA16(af0, bf0, 0);
        LDA4(af1, 1, 0, sA);
        if (s1) { STB(2, ktn, sB1); STB(3, ktn, sB1); }
        MFMA16(af1, bf0, 1);
        LDA4(af0, 0, 1, sA); LDB4(bf1, 1, sB);
        if (s2) { STA(0, ktn2, sA2); STA(1, ktn2, sA2); }
        MFMA16(af0, bf1, 0);
        LDA4(af1, 1, 1, sA);
        if (s2) { STA(2, ktn2, sA2); STA(3, ktn2, sA2); }
        MFMA16(af1, bf1, 1);

        sA += 2; if (sA >= 5) sA -= 5;
        sB += 2; if (sB >= 5) sB -= 5;
        sB1 += 2; if (sB1 >= 5) sB1 -= 5;
        sA2 += 2; if (sA2 >= 5) sA2 -= 5;
    }

    // ---- epilogue: C/D col=lane&15, row=(lane>>4)*4+reg; scale by sx*sw ----
    const int crow0 = bm * 256 + wr * 128 + (lane >> 4) * 4;
    const int ccol0 = bn * 256 + wc * 64 + (lane & 15);
#pragma unroll
    for (int n = 0; n < 4; ++n) {
        const float swn = sw[ccol0 + n * 16];
#pragma unroll
        for (int m = 0; m < 8; ++m)
#pragma unroll
            for (int r = 0; r < 4; ++r) {
                const int row_ = crow0 + m * 16 + r;
                C[(size_t)row_ * N + ccol0 + n * 16] =
                    sx[row_] * swn * (float)acc[m][n][r];
            }
    }
}

// ---------------- launch ----------------
extern "C" void kernel_launch(void* const* d_in, const int* in_sizes, int n_in,
                              void* d_out, int out_size, void* d_ws, size_t ws_size,
                              hipStream_t stream) {
    const float* x        = (const float*)d_in[0];
    const int* packed     = (const int*)d_in[1];
    const float* scales   = (const float*)d_in[2];
    const void* vals      = (const void*)d_in[3];
    const int* idxs       = (const int*)d_in[4];
    const int* ptr        = (const int*)d_in[5];
    float* out            = (float*)d_out;

    char* ws = (char*)d_ws;
    int* Wq   = (int*)ws;                              // 16 MB
    int* Xq   = (int*)(ws + (size_t)16 * 1024 * 1024); // 16 MB
    float* sw = (float*)(ws + (size_t)32 * 1024 * 1024);
    float* sx = (float*)(ws + (size_t)32 * 1024 * 1024 + 16384);

    prep_kernel<<<8192, 256, 0, stream>>>(packed, scales, vals, idxs, ptr,
                                          Wq, x, Xq, sw, sx);
    gemm_bt_kernel<<<256, 512, 0, stream>>>((const signed char*)Xq,
                                            (const signed char*)Wq, sx, sw, out);
}

// Round 12
// 99.081 us; speedup vs baseline: 2.0964x; 1.0060x over previous
//
#include <hip/hip_runtime.h>
#include <hip/hip_fp16.h>

// ---------------- types ----------------
typedef __attribute__((ext_vector_type(4))) int i32x4;

#define GLOBAL_AS __attribute__((address_space(1)))
#define LDS_AS __attribute__((address_space(3)))

static __device__ __forceinline__ void gload16(const void* g, void* l) {
    __builtin_amdgcn_global_load_lds((const GLOBAL_AS void*)g, (LDS_AS void*)l, 16, 0, 0);
}

#define SBAR() __builtin_amdgcn_s_barrier()
#define WAITVM(N) asm volatile("s_waitcnt vmcnt(" #N ")" ::: "memory")

static __device__ __forceinline__ int q8(float v, float inv) {
    int q = (int)rintf(v * inv);
    q = q > 127 ? 127 : q;
    q = q < -127 ? -127 : q;
    return q & 255;
}

// ---------------- kernel 1: fused prep -> int8 operands (unchanged from r11) ----------------
// blocks [0,4096): W row -> i8 (int4 dequant + CSR outliers, per-row absmax scale)
// blocks [4096,8192): X row -> i8 (per-token-row absmax scale)
__global__ __launch_bounds__(256) void prep_kernel(
    const int* __restrict__ packed,      // [4096][2048]
    const float* __restrict__ scales,    // [4096]
    const void* __restrict__ vals,       // [nnz] dtype auto-detected (round-1 finding)
    const int* __restrict__ idxs,        // [nnz]
    const int* __restrict__ ptr,         // [4097]
    int* __restrict__ Wq,                // [4096][1024] ints (4096 i8/row)
    const float* __restrict__ x,
    int* __restrict__ Xq,                // [4096][1024] ints
    float* __restrict__ sw,              // [4096] W row scales
    float* __restrict__ sx)              // [4096] X row scales
{
    const int tid = threadIdx.x;
    __shared__ float smax[4];
    if (blockIdx.x >= 4096) {
        // ---- X row quantize ----
        const int row = blockIdx.x - 4096;
        const float4* xp4 = (const float4*)(x + (size_t)row * 4096);
        float4 v0 = xp4[tid], v1 = xp4[tid + 256], v2 = xp4[tid + 512], v3 = xp4[tid + 768];
        float am = fabsf(v0.x);
        am = fmaxf(am, fabsf(v0.y)); am = fmaxf(am, fabsf(v0.z)); am = fmaxf(am, fabsf(v0.w));
        am = fmaxf(am, fabsf(v1.x)); am = fmaxf(am, fabsf(v1.y)); am = fmaxf(am, fabsf(v1.z)); am = fmaxf(am, fabsf(v1.w));
        am = fmaxf(am, fabsf(v2.x)); am = fmaxf(am, fabsf(v2.y)); am = fmaxf(am, fabsf(v2.z)); am = fmaxf(am, fabsf(v2.w));
        am = fmaxf(am, fabsf(v3.x)); am = fmaxf(am, fabsf(v3.y)); am = fmaxf(am, fabsf(v3.z)); am = fmaxf(am, fabsf(v3.w));
        for (int o = 32; o; o >>= 1) am = fmaxf(am, __shfl_xor(am, o));
        if ((tid & 63) == 0) smax[tid >> 6] = am;
        __syncthreads();
        am = fmaxf(fmaxf(smax[0], smax[1]), fmaxf(smax[2], smax[3]));
        const float sc_ = am > 1e-30f ? am / 127.0f : 0.0f;
        const float inv = am > 1e-30f ? 127.0f / am : 0.0f;
        if (tid == 0) sx[row] = sc_;
        int* orow = Xq + (size_t)row * 1024;
        orow[tid]       = q8(v0.x,inv) | (q8(v0.y,inv)<<8) | (q8(v0.z,inv)<<16) | (q8(v0.w,inv)<<24);
        orow[tid + 256] = q8(v1.x,inv) | (q8(v1.y,inv)<<8) | (q8(v1.z,inv)<<16) | (q8(v1.w,inv)<<24);
        orow[tid + 512] = q8(v2.x,inv) | (q8(v2.y,inv)<<8) | (q8(v2.z,inv)<<16) | (q8(v2.w,inv)<<24);
        orow[tid + 768] = q8(v3.x,inv) | (q8(v3.y,inv)<<8) | (q8(v3.z,inv)<<16) | (q8(v3.w,inv)<<24);
        return;
    }
    // ---- W row dequant + outliers -> i8 ----
    __shared__ float sp[4096];
    __shared__ int sdet[3];
    const int row = blockIdx.x;
    float4* sp4 = (float4*)sp;
    const float4 z4 = make_float4(0.f, 0.f, 0.f, 0.f);
    for (int i = tid; i < 1024; i += 256) sp4[i] = z4;
    {   // parallel dtype detect (wave w scores interpretation w)
        const int wvp = tid >> 6, ln = tid & 63;
        if (wvp < 3) {
            int c = 0;
            for (int i = ln; i < 192; i += 64) {
                float a;
                if (wvp == 0) a = fabsf(((const float*)vals)[i]);
                else if (wvp == 1) a = fabsf(__half2float(((const __half*)vals)[i]));
                else { union { unsigned u; float fv; } cc;
                       cc.u = ((unsigned)((const unsigned short*)vals)[i]) << 16;
                       a = fabsf(cc.fv); }
                c += (a >= 1e-5f && a <= 0.5f) ? 1 : 0;
            }
            for (int o = 32; o; o >>= 1) c += __shfl_down(c, o);
            if (ln == 0) sdet[wvp] = c;
        }
    }
    __syncthreads();
    const int kind = (sdet[0] >= sdet[1] && sdet[0] >= sdet[2]) ? 0 : (sdet[1] >= sdet[2] ? 1 : 2);
    const int s = ptr[row], e = ptr[row + 1];
    if (kind == 0) {
        const float* vf = (const float*)vals;
        for (int i = s + tid; i < e; i += 256) atomicAdd(&sp[idxs[i]], vf[i]);
    } else if (kind == 1) {
        const __half* vh = (const __half*)vals;
        for (int i = s + tid; i < e; i += 256) atomicAdd(&sp[idxs[i]], __half2float(vh[i]));
    } else {
        const unsigned short* vb = (const unsigned short*)vals;
        for (int i = s + tid; i < e; i += 256) {
            union { unsigned u; float fv; } c; c.u = ((unsigned)vb[i]) << 16;
            atomicAdd(&sp[idxs[i]], c.fv);
        }
    }
    __syncthreads();
    const float scr = scales[row];
    const int* prow = packed + (size_t)row * 2048;
    float am = 0.0f;
    for (int j = tid; j < 2048; j += 256) {
        const int p = prow[j];
        const float lo = (float)((p & 0xF) - 8) * scr + sp[2 * j];
        const float hi = (float)(((p >> 4) & 0xF) - 8) * scr + sp[2 * j + 1];
        sp[2 * j] = lo; sp[2 * j + 1] = hi;
        am = fmaxf(am, fmaxf(fabsf(lo), fabsf(hi)));
    }
    for (int o = 32; o; o >>= 1) am = fmaxf(am, __shfl_xor(am, o));
    if ((tid & 63) == 0) smax[tid >> 6] = am;
    __syncthreads();
    am = fmaxf(fmaxf(smax[0], smax[1]), fmaxf(smax[2], smax[3]));
    const float sc2 = am > 1e-30f ? am / 127.0f : 0.0f;
    const float inv2 = am > 1e-30f ? 127.0f / am : 0.0f;
    if (tid == 0) sw[row] = sc2;
    int* wrow = Wq + (size_t)row * 1024;
    for (int j = tid; j < 1024; j += 256) {
        const float* c4 = sp + 4 * j;
        wrow[j] = q8(c4[0],inv2) | (q8(c4[1],inv2)<<8) | (q8(c4[2],inv2)<<16) | (q8(c4[3],inv2)<<24);
    }
}

// ---------------- kernel 2: 256x256 i8 GEMM, r11 + quadrant-ahead prefetch ----------------
// C[M,N] = sx[m]*sw[n]*(Xq . Wq^T), mfma_i32_16x16x64_i8, 8 waves (2Mx4N),
// BK=128B, 5x32KB circular slots, one WAITVM(4)+SBAR per K-tile (r11 ledger).
// Round-12 change: quadrant q+1's ds_reads are issued BEFORE cluster q's MFMAs
// with distinct frag registers (af0..af3,bf0,bf1) -- breaks the per-wave
// read->MFMA->read serialization so the LDS pipe (192 reads/tile, ~2300cyc)
// overlaps the MFMA pipe instead of alternating with it.
__global__ __launch_bounds__(512, 2) void gemm_bt_kernel(
    const signed char* __restrict__ A,   // i8, M x 4096
    const signed char* __restrict__ B,   // i8, N x 4096
    const float* __restrict__ sx,        // [M]
    const float* __restrict__ sw,        // [N]
    float* __restrict__ C)               // fp32, M x N
{
    constexpr int KB = 4096;             // K bytes per row
    constexpr int N = 4096;
    constexpr int NT = 32;               // 4096 / 128
    __shared__ __attribute__((aligned(128))) char smem[163840]; // 5 x 32KB slots

    const int tid = threadIdx.x;
    const int lane = tid & 63;
    const int wv = tid >> 6;
    const int bid = (blockIdx.x & 7) * 32 + (blockIdx.x >> 3);  // bijective XCD swizzle
    const int bm = bid >> 4;
    const int bn = bid & 15;

    // ---- staging: one gload16 round (512x16B = 8KB) = 64 rows x 128B ----
    const int grow = tid >> 3;
    const int sg = (tid & 7) ^ (grow & 7);              // pre-swizzled 16B segment
    const signed char* ag = A + (size_t)(bm * 256 + grow) * KB + sg * 16;
    const signed char* bg = B + (size_t)(bn * 256 + grow) * KB + sg * 16;

#define STA(R, KTB, SLOT)                                                              \
    gload16(ag + (size_t)((R) * 64) * KB + (KTB),                                      \
            smem + (SLOT) * 32768 + (R) * 8192 + wv * 1024);
#define STB(R, KTB, SLOT)                                                              \
    gload16(bg + (size_t)((R) * 64) * KB + (KTB),                                      \
            smem + (SLOT) * 32768 + (R) * 8192 + wv * 1024);

    // ---- fragment read geometry (16x16x64 i8) ----
    const int wr = wv >> 2, wc = wv & 3;
    const int rowa = wr * 128 + (lane & 15);
    const int rowb = wc * 64 + (lane & 15);
    const int khw = lane >> 4;
    const int rx = lane & 7;

#define LDA4(DST, MH, KK, SLOT)                                                        \
    {                                                                                  \
        _Pragma("unroll") for (int m = 0; m < 4; ++m) {                                \
            const int row_ = rowa + (MH) * 64 + m * 16;                                \
            DST[m] = *(const i32x4*)(smem + (SLOT) * 32768 + row_ * 128 +              \
                                     (((((KK) << 2) + khw) ^ rx) << 4));               \
        }                                                                              \
    }
#define LDB4(DST, KK, SLOT)                                                            \
    {                                                                                  \
        _Pragma("unroll") for (int n = 0; n < 4; ++n) {                                \
            const int row_ = rowb + n * 16;                                            \
            DST[n] = *(const i32x4*)(smem + (SLOT) * 32768 + row_ * 128 +              \
                                     (((((KK) << 2) + khw) ^ rx) << 4));               \
        }                                                                              \
    }
#define MFMA16(AF, BF, MH)                                                             \
    {                                                                                  \
        __builtin_amdgcn_s_setprio(1);                                                 \
        _Pragma("unroll") for (int m = 0; m < 4; ++m)                                  \
            _Pragma("unroll") for (int n = 0; n < 4; ++n)                              \
                acc[(MH) * 4 + m][n] = __builtin_amdgcn_mfma_i32_16x16x64_i8(          \
                    AF[m], BF[n], acc[(MH) * 4 + m][n], 0, 0, 0);                      \
        __builtin_amdgcn_s_setprio(0);                                                 \
    }

    i32x4 acc[8][4];
#pragma unroll
    for (int m = 0; m < 8; ++m)
#pragma unroll
        for (int n = 0; n < 4; ++n) acc[m][n] = (i32x4)0;

    // ---- prologue: A(0)@s0, B(0)@s1, A(1)@s2 ----
#pragma unroll
    for (int r = 0; r < 4; ++r) STA(r, 0, 0);
#pragma unroll
    for (int r = 0; r < 4; ++r) STB(r, 0, 1);
#pragma unroll
    for (int r = 0; r < 4; ++r) STA(r, 128, 2);

    int sA = 0, sB = 1, sB1 = 3, sA2 = 4;
    for (int t = 0; t < NT; ++t) {
        const int ktn = (t + 1) * 128;
        const int ktn2 = (t + 2) * 128;
        const bool s1 = (t + 1 < NT), s2 = (t + 2 < NT);
        if (s1) { WAITVM(4); } else { WAITVM(0); }
        SBAR();
        __builtin_amdgcn_sched_barrier(0);

        // q0..q3 = (mh,kk) in order (0,0),(1,0),(0,1),(1,1).
        // Reads for q+1 are issued BEFORE cluster q (distinct registers).
        i32x4 af0[4], af1[4], af2[4], af3[4], bf0[4], bf1[4];
        LDA4(af0, 0, 0, sA); LDB4(bf0, 0, sB);      // q0 frags
        LDA4(af1, 1, 0, sA);                        // q1 prefetch
        if (s1) { STB(0, ktn, sB1); STB(1, ktn, sB1); }
        MFMA16(af0, bf0, 0);                        // q0
        LDA4(af2, 0, 1, sA); LDB4(bf1, 1, sB);      // q2 prefetch
        if (s1) { STB(2, ktn, sB1); STB(3, ktn, sB1); }
        MFMA16(af1, bf0, 1);                        // q1
        LDA4(af3, 1, 1, sA);                        // q3 prefetch
        if (s2) { STA(0, ktn2, sA2); STA(1, ktn2, sA2); }
        MFMA16(af2, bf1, 0);                        // q2
        if (s2) { STA(2, ktn2, sA2); STA(3, ktn2, sA2); }
        MFMA16(af3, bf1, 1);                        // q3

        sA += 2; if (sA >= 5) sA -= 5;
        sB += 2; if (sB >= 5) sB -= 5;
        sB1 += 2; if (sB1 >= 5) sB1 -= 5;
        sA2 += 2; if (sA2 >= 5) sA2 -= 5;
    }

    // ---- epilogue: C/D col=lane&15, row=(lane>>4)*4+reg; scale by sx*sw ----
    const int crow0 = bm * 256 + wr * 128 + (lane >> 4) * 4;
    const int ccol0 = bn * 256 + wc * 64 + (lane & 15);
#pragma unroll
    for (int n = 0; n < 4; ++n) {
        const float swn = sw[ccol0 + n * 16];
#pragma unroll
        for (int m = 0; m < 8; ++m)
#pragma unroll
            for (int r = 0; r < 4; ++r) {
                const int row_ = crow0 + m * 16 + r;
                C[(size_t)row_ * N + ccol0 + n * 16] =
                    sx[row_] * swn * (float)acc[m][n][r];
            }
    }
}

// ---------------- launch ----------------
extern "C" void kernel_launch(void* const* d_in, const int* in_sizes, int n_in,
                              void* d_out, int out_size, void* d_ws, size_t ws_size,
                              hipStream_t stream) {
    const float* x        = (const float*)d_in[0];
    const int* packed     = (const int*)d_in[1];
    const float* scales   = (const float*)d_in[2];
    const void* vals      = (const void*)d_in[3];
    const int* idxs       = (const int*)d_in[4];
    const int* ptr        = (const int*)d_in[5];
    float* out            = (float*)d_out;

    char* ws = (char*)d_ws;
    int* Wq   = (int*)ws;                              // 16 MB
    int* Xq   = (int*)(ws + (size_t)16 * 1024 * 1024); // 16 MB
    float* sw = (float*)(ws + (size_t)32 * 1024 * 1024);
    float* sx = (float*)(ws + (size_t)32 * 1024 * 1024 + 16384);

    prep_kernel<<<8192, 256, 0, stream>>>(packed, scales, vals, idxs, ptr,
                                          Wq, x, Xq, sw, sx);
    gemm_bt_kernel<<<256, 512, 0, stream>>>((const signed char*)Xq,
                                            (const signed char*)Wq, sx, sw, out);
}